// Round 4
// baseline (432.112 us; speedup 1.0000x reference)
//
#include <hip/hip_runtime.h>
#include <math.h>
#include <stdint.h>

#define DIM   1024
#define NH    16
#define HD    64
#define BATCH 2
#define SEQ   2048
#define ROWS  (BATCH*SEQ)   // 4096

typedef __attribute__((ext_vector_type(8))) short short8;   // 8 x bf16 (4 VGPR)
typedef __attribute__((ext_vector_type(4))) float f32x4;

// ---- bf16 split helpers (RNE) ----------------------------------------------
__device__ __forceinline__ unsigned short f2bf(float f) {
    union { float f; unsigned u; } x; x.f = f;
    unsigned r = x.u + 0x7FFFu + ((x.u >> 16) & 1u);
    return (unsigned short)(r >> 16);
}
__device__ __forceinline__ float bf2f(unsigned short h) {
    union { unsigned u; float f; } x; x.u = ((unsigned)h) << 16;
    return x.f;
}

#define MFMA(a,b,c) __builtin_amdgcn_mfma_f32_16x16x32_bf16((a),(b),(c),0,0,0)

// async global->LDS, 16B per lane. LDS dest must be linear (base + lane*16).
__device__ __forceinline__ void gl_lds16(const void* g, void* l) {
    __builtin_amdgcn_global_load_lds(
        (const __attribute__((address_space(1))) unsigned int*)g,
        (__attribute__((address_space(3))) unsigned int*)l,
        16, 0, 0);
}

// ---------------------------------------------------------------------------
// split x -> Xh, Xl bf16 planes
// ---------------------------------------------------------------------------
__global__ __launch_bounds__(256) void splitx_kernel(
    const float* __restrict__ x, unsigned short* __restrict__ xh, unsigned short* __restrict__ xl)
{
    const size_t i = ((size_t)blockIdx.x * 256 + threadIdx.x) * 4;
    const float4 v = *(const float4*)&x[i];
    ushort4 h, l;
    h.x = f2bf(v.x); l.x = f2bf(v.x - bf2f(h.x));
    h.y = f2bf(v.y); l.y = f2bf(v.y - bf2f(h.y));
    h.z = f2bf(v.z); l.z = f2bf(v.z - bf2f(h.z));
    h.w = f2bf(v.w); l.w = f2bf(v.w - bf2f(h.w));
    *(ushort4*)&xh[i] = h;
    *(ushort4*)&xl[i] = l;
}

// ---------------------------------------------------------------------------
// transpose + split the four 1024x1024 weights: WT[n][k] hi/lo bf16
// ---------------------------------------------------------------------------
__global__ __launch_bounds__(256) void splitw_kernel(
    const float* __restrict__ w0, const float* __restrict__ w1,
    const float* __restrict__ w2, const float* __restrict__ w3,
    unsigned short* __restrict__ wth, unsigned short* __restrict__ wtl)
{
    __shared__ float tile[64][68];
    const int z = blockIdx.z;
    const float* W = (z == 0) ? w0 : (z == 1) ? w1 : (z == 2) ? w2 : w3;
    unsigned short* th = wth + (size_t)z * DIM * DIM;
    unsigned short* tl = wtl + (size_t)z * DIM * DIM;
    const int k0 = blockIdx.y * 64, n0 = blockIdx.x * 64;
    const int tr = threadIdx.x >> 4, tc = (threadIdx.x & 15) * 4;
    #pragma unroll
    for (int p = 0; p < 4; ++p) {
        const float4 v = *(const float4*)&W[(size_t)(k0 + tr + p*16) * DIM + n0 + tc];
        *(float4*)&tile[tr + p*16][tc] = v;
    }
    __syncthreads();
    #pragma unroll
    for (int p = 0; p < 4; ++p) {
        const int n = tr + p*16;
        ushort4 hv, lv;
        float v0 = tile[tc+0][n], v1 = tile[tc+1][n], v2 = tile[tc+2][n], v3 = tile[tc+3][n];
        hv.x = f2bf(v0); lv.x = f2bf(v0 - bf2f(hv.x));
        hv.y = f2bf(v1); lv.y = f2bf(v1 - bf2f(hv.y));
        hv.z = f2bf(v2); lv.z = f2bf(v2 - bf2f(hv.z));
        hv.w = f2bf(v3); lv.w = f2bf(v3 - bf2f(hv.w));
        *(ushort4*)&th[(size_t)(n0 + n) * DIM + k0 + tc] = hv;
        *(ushort4*)&tl[(size_t)(n0 + n) * DIM + k0 + tc] = lv;
    }
}

// ---------------------------------------------------------------------------
// split-bf16 3-term MFMA GEMM, 128x128 tile, BK=32, global_load_lds staging,
// double-buffered LDS, one barrier per k-step.
// ---------------------------------------------------------------------------
template<int MODE>
__global__ __launch_bounds__(256, 2) void gemm3_kernel(
    const unsigned short* __restrict__ Ah, const unsigned short* __restrict__ Al,
    const unsigned short* __restrict__ Wh0, const unsigned short* __restrict__ Wl0,
    const unsigned short* __restrict__ Wh1, const unsigned short* __restrict__ Wl1,
    const unsigned short* __restrict__ Wh2, const unsigned short* __restrict__ Wl2,
    const float* __restrict__ b0, const float* __restrict__ b1, const float* __restrict__ b2,
    const float* __restrict__ fc, const float* __restrict__ fs,
    unsigned short* __restrict__ q_h, unsigned short* __restrict__ q_l,
    unsigned short* __restrict__ k_h, unsigned short* __restrict__ k_l,
    unsigned short* __restrict__ vt_h, unsigned short* __restrict__ vt_l,
    float* __restrict__ outf)
{
    __shared__ __align__(16) unsigned short lah[2][128*32], lal[2][128*32];
    __shared__ __align__(16) unsigned short lbh[2][128*32], lbl[2][128*32];

    const int tid = threadIdx.x;
    const int lane = tid & 63;
    const int lx = lane & 15, lg = lane >> 4;
    const int wv = tid >> 6, wm = wv >> 1, wn = wv & 1;
    const int n0 = blockIdx.x * 128, m0 = blockIdx.y * 128;
    const int z = (MODE == 0) ? blockIdx.z : 3;

    const unsigned short *Wh, *Wl;
    const float* bias;
    if (MODE == 0) {
        Wh = (z == 0) ? Wh0 : (z == 1) ? Wh1 : Wh2;
        Wl = (z == 0) ? Wl0 : (z == 1) ? Wl1 : Wl2;
        bias = (z == 0) ? b0 : (z == 1) ? b1 : b2;
    } else { Wh = Wh0; Wl = Wl0; bias = nullptr; }

    const int sr  = tid >> 2;          // staging row 0..63 (and +64)
    const int scb = (tid & 3) * 16;    // byte col within 64B row
    const int ldso = tid * 16;         // linear LDS byte offset (wave-linear)

    f32x4 acc[4][4] = {};

    auto STAGE = [&](int k0i, int buf) {
        const char* a0 = (const char*)Ah + ((size_t)(m0 + sr) * DIM + k0i) * 2 + scb;
        const char* l0 = (const char*)Al + ((size_t)(m0 + sr) * DIM + k0i) * 2 + scb;
        const char* bb = (const char*)Wh + ((size_t)(n0 + sr) * DIM + k0i) * 2 + scb;
        const char* bl = (const char*)Wl + ((size_t)(n0 + sr) * DIM + k0i) * 2 + scb;
        const size_t rstep = (size_t)64 * DIM * 2;
        gl_lds16(a0,         (char*)&lah[buf][0] + ldso);
        gl_lds16(a0 + rstep, (char*)&lah[buf][0] + ldso + 4096);
        gl_lds16(l0,         (char*)&lal[buf][0] + ldso);
        gl_lds16(l0 + rstep, (char*)&lal[buf][0] + ldso + 4096);
        gl_lds16(bb,         (char*)&lbh[buf][0] + ldso);
        gl_lds16(bb + rstep, (char*)&lbh[buf][0] + ldso + 4096);
        gl_lds16(bl,         (char*)&lbl[buf][0] + ldso);
        gl_lds16(bl + rstep, (char*)&lbl[buf][0] + ldso + 4096);
    };

    STAGE(0, 0);
    __syncthreads();

    for (int kt = 0; kt < DIM/32; ++kt) {
        const int cur = kt & 1;
        if (kt + 1 < DIM/32) STAGE((kt + 1) * 32, cur ^ 1);

        short8 afh[4], afl[4], bfh[4], bfl[4];
        #pragma unroll
        for (int i = 0; i < 4; ++i) {
            const int ar = wm*64 + i*16 + lx;
            afh[i] = *(const short8*)((const char*)&lah[cur][0] + ar*64 + lg*16);
            afl[i] = *(const short8*)((const char*)&lal[cur][0] + ar*64 + lg*16);
            const int br = wn*64 + i*16 + lx;
            bfh[i] = *(const short8*)((const char*)&lbh[cur][0] + br*64 + lg*16);
            bfl[i] = *(const short8*)((const char*)&lbl[cur][0] + br*64 + lg*16);
        }
        #pragma unroll
        for (int i = 0; i < 4; ++i)
        #pragma unroll
        for (int jn = 0; jn < 4; ++jn) {
            acc[i][jn] = MFMA(afh[i], bfh[jn], acc[i][jn]);
            acc[i][jn] = MFMA(afh[i], bfl[jn], acc[i][jn]);
            acc[i][jn] = MFMA(afl[i], bfh[jn], acc[i][jn]);
        }
        __syncthreads();
    }

    // epilogue
    #pragma unroll
    for (int i = 0; i < 4; ++i) {
        const int tokbase = m0 + wm*64 + i*16 + lg*4;
        #pragma unroll
        for (int jn = 0; jn < 4; ++jn) {
            const int c = n0 + wn*64 + jn*16 + lx;
            float bv = (MODE == 0) ? bias[c] : 0.f;
            float vj[4];
            #pragma unroll
            for (int j = 0; j < 4; ++j) vj[j] = acc[i][jn][j] + bv;
            if (MODE == 0 && z < 2) {
                const int i0 = (c & 63) >> 1;
                #pragma unroll
                for (int j = 0; j < 4; ++j) {
                    const int s = (tokbase + j) & (SEQ - 1);
                    const float cv = fc[s*32 + i0], sv = fs[s*32 + i0];
                    const float pv = __shfl_xor(vj[j], 1);
                    vj[j] = (c & 1) ? (pv*sv + vj[j]*cv) : (vj[j]*cv - pv*sv);
                }
            }
            if (MODE == 1) {
                #pragma unroll
                for (int j = 0; j < 4; ++j)
                    outf[(size_t)(tokbase + j) * DIM + c] = vj[j];
            } else if (z < 2) {
                unsigned short* oh = z ? k_h : q_h;
                unsigned short* ol = z ? k_l : q_l;
                #pragma unroll
                for (int j = 0; j < 4; ++j) {
                    const unsigned short hi = f2bf(vj[j]);
                    oh[(size_t)(tokbase + j) * DIM + c] = hi;
                    ol[(size_t)(tokbase + j) * DIM + c] = f2bf(vj[j] - bf2f(hi));
                }
            } else {
                const int bb = tokbase >> 11, s0 = tokbase & (SEQ - 1);
                const int hh = c >> 6, d = c & 63;
                const size_t vb = ((size_t)(bb*NH + hh) * HD + d) * SEQ + s0;
                ushort4 hv, lv;
                #pragma unroll
                for (int j = 0; j < 4; ++j) {
                    const unsigned short hi = f2bf(vj[j]);
                    ((unsigned short*)&hv)[j] = hi;
                    ((unsigned short*)&lv)[j] = f2bf(vj[j] - bf2f(hi));
                }
                *(ushort4*)&vt_h[vb] = hv;
                *(ushort4*)&vt_l[vb] = lv;
            }
        }
    }
}

// ---------------------------------------------------------------------------
// MFMA flash attention. 512 thr = 8 waves, Q-tile 256 (32 q/wave, 2 frags),
// K/V 64-row tiles double-buffered, 3-bit XOR swizzle (conflict-free b128),
// staged via global_load_lds with pre-swizzled global source. One barrier/tile.
// grid (SEQ/256, NH, BATCH) = 256 blocks = 1/CU.
// ---------------------------------------------------------------------------
__global__ __launch_bounds__(512, 2) void attn_kernel(
    const unsigned short* __restrict__ Qh, const unsigned short* __restrict__ Ql,
    const unsigned short* __restrict__ Kh, const unsigned short* __restrict__ Kl,
    const unsigned short* __restrict__ Vth, const unsigned short* __restrict__ Vtl,
    const float* __restrict__ mask,
    unsigned short* __restrict__ AOh, unsigned short* __restrict__ AOl)
{
    __shared__ __align__(16) unsigned short kbh[2][64*64], kbl[2][64*64];
    __shared__ __align__(16) unsigned short vbh[2][64*64], vbl[2][64*64];
    __shared__ __align__(16) unsigned short pbh[8][2][16*64], pbl[8][2][16*64];

    const int tid = threadIdx.x;
    const int w = tid >> 6, lane = tid & 63;
    const int lx = lane & 15, lg = lane >> 4;
    const int qblk = blockIdx.x * 256;
    const int h = blockIdx.y, b = blockIdx.z;

    const int qrow0 = qblk + w*32 + lx;          // frag 0 softmax row
    const int qrow1 = qrow0 + 16;                // frag 1

    short8 qf[2][2][2];                          // [frag][plane][ks]
    {
        const size_t base0 = ((size_t)b*SEQ + qrow0) * DIM + h*HD + lg*8;
        const size_t base1 = ((size_t)b*SEQ + qrow1) * DIM + h*HD + lg*8;
        qf[0][0][0] = *(const short8*)&Qh[base0];  qf[0][0][1] = *(const short8*)&Qh[base0 + 32];
        qf[0][1][0] = *(const short8*)&Ql[base0];  qf[0][1][1] = *(const short8*)&Ql[base0 + 32];
        qf[1][0][0] = *(const short8*)&Qh[base1];  qf[1][0][1] = *(const short8*)&Qh[base1 + 32];
        qf[1][1][0] = *(const short8*)&Ql[base1];  qf[1][1][1] = *(const short8*)&Ql[base1 + 32];
    }

    float m_st[2] = {-INFINITY, -INFINITY}, l_st[2] = {0.f, 0.f};
    f32x4 acc[2][4] = {};

    // staging: 512 threads cover one 64x64 bf16 plane (8KB) per shot
    const int sr  = tid >> 3;                       // row 0..63
    const int gco = ((tid & 7) * 16) ^ ((sr & 7) << 4);   // pre-swizzled byte col
    const int ldso = tid * 16;                      // linear LDS dest

    const char* khs = (const char*)Kh + ((size_t)b*SEQ + sr) * DIM * 2 + h*128 + gco;
    const char* kls = (const char*)Kl + ((size_t)b*SEQ + sr) * DIM * 2 + h*128 + gco;
    const char* vhs = (const char*)Vth + ((size_t)(b*NH + h)*HD + sr) * SEQ * 2 + gco;
    const char* vls = (const char*)Vtl + ((size_t)(b*NH + h)*HD + sr) * SEQ * 2 + gco;

    auto STAGE = [&](int t, int buf) {
        const size_t ko = (size_t)t * 64 * DIM * 2;
        const size_t vo = (size_t)t * 128;
        gl_lds16(khs + ko, (char*)&kbh[buf][0] + ldso);
        gl_lds16(kls + ko, (char*)&kbl[buf][0] + ldso);
        gl_lds16(vhs + vo, (char*)&vbh[buf][0] + ldso);
        gl_lds16(vls + vo, (char*)&vbl[buf][0] + ldso);
    };

    STAGE(0, 0);
    __syncthreads();

    const float* mrow0 = mask + (size_t)qrow0 * SEQ;
    const float* mrow1 = mask + (size_t)qrow1 * SEQ;

    for (int t = 0; t < SEQ/64; ++t) {
        const int cur = t & 1;
        if (t + 1 < SEQ/64) STAGE(t + 1, cur ^ 1);

        // mask prefetch (k = 16mf + 4lg + j)
        float4 mk[2][4];
        #pragma unroll
        for (int mf = 0; mf < 4; ++mf) {
            mk[0][mf] = *(const float4*)&mrow0[t*64 + mf*16 + lg*4];
            mk[1][mf] = *(const float4*)&mrow1[t*64 + mf*16 + lg*4];
        }

        // --- S^T = K · Q^T, both q-frags share every K fragment read ---
        f32x4 st[2][4] = {};
        #pragma unroll
        for (int ks = 0; ks < 2; ++ks) {
            #pragma unroll
            for (int mf = 0; mf < 4; ++mf) {
                const int row = mf*16 + lx;
                const int off = row*128 + ((ks*64 + lg*16) ^ ((row & 7) << 4));
                const short8 akh = *(const short8*)((const char*)&kbh[cur][0] + off);
                const short8 akl = *(const short8*)((const char*)&kbl[cur][0] + off);
                #pragma unroll
                for (int f = 0; f < 2; ++f) {
                    st[f][mf] = MFMA(akh, qf[f][0][ks], st[f][mf]);
                    st[f][mf] = MFMA(akh, qf[f][1][ks], st[f][mf]);
                    st[f][mf] = MFMA(akl, qf[f][0][ks], st[f][mf]);
                }
            }
        }

        // --- online softmax per frag (lane owns q-col lx) ---
        #pragma unroll
        for (int f = 0; f < 2; ++f) {
            float p[4][4];
            float mx = -INFINITY;
            #pragma unroll
            for (int mf = 0; mf < 4; ++mf) {
                p[mf][0] = st[f][mf][0]*0.125f + mk[f][mf].x;
                p[mf][1] = st[f][mf][1]*0.125f + mk[f][mf].y;
                p[mf][2] = st[f][mf][2]*0.125f + mk[f][mf].z;
                p[mf][3] = st[f][mf][3]*0.125f + mk[f][mf].w;
                mx = fmaxf(mx, fmaxf(fmaxf(p[mf][0], p[mf][1]), fmaxf(p[mf][2], p[mf][3])));
            }
            mx = fmaxf(mx, __shfl_xor(mx, 16));
            mx = fmaxf(mx, __shfl_xor(mx, 32));
            const float mnew = fmaxf(m_st[f], mx);
            const float scl = __expf(m_st[f] - mnew);
            m_st[f] = mnew;

            float ps = 0.f;
            #pragma unroll
            for (int mf = 0; mf < 4; ++mf) {
                unsigned hw0, hw1, lw0, lw1;
                #pragma unroll
                for (int j = 0; j < 4; ++j) {
                    const float e = __expf(p[mf][j] - mnew);
                    ps += e;
                    const unsigned short hi = f2bf(e);
                    const unsigned short lo = f2bf(e - bf2f(hi));
                    if (j == 0)      { hw0 = hi;  lw0 = lo; }
                    else if (j == 1) { hw0 |= (unsigned)hi << 16; lw0 |= (unsigned)lo << 16; }
                    else if (j == 2) { hw1 = hi;  lw1 = lo; }
                    else             { hw1 |= (unsigned)hi << 16; lw1 |= (unsigned)lo << 16; }
                }
                const int off = lx*128 + ((mf*32 + lg*8) ^ ((lx & 7) << 4));
                *(uint2*)((char*)&pbh[w][f][0] + off) = make_uint2(hw0, hw1);
                *(uint2*)((char*)&pbl[w][f][0] + off) = make_uint2(lw0, lw1);
            }
            ps += __shfl_xor(ps, 16);
            ps += __shfl_xor(ps, 32);
            l_st[f] = l_st[f]*scl + ps;

            float fj[4];
            #pragma unroll
            for (int j = 0; j < 4; ++j) fj[j] = __shfl(scl, lg*4 + j);
            #pragma unroll
            for (int nf = 0; nf < 4; ++nf)
                #pragma unroll
                for (int j = 0; j < 4; ++j) acc[f][nf][j] *= fj[j];
        }

        // --- O += P · V, both frags share every V fragment read ---
        #pragma unroll
        for (int ks = 0; ks < 2; ++ks) {
            short8 pa[2][2];
            #pragma unroll
            for (int f = 0; f < 2; ++f) {
                const int poff = lx*128 + ((ks*64 + lg*16) ^ ((lx & 7) << 4));
                pa[f][0] = *(const short8*)((const char*)&pbh[w][f][0] + poff);
                pa[f][1] = *(const short8*)((const char*)&pbl[w][f][0] + poff);
            }
            #pragma unroll
            for (int nf = 0; nf < 4; ++nf) {
                const int row = nf*16 + lx;
                const int off = row*128 + ((ks*64 + lg*16) ^ ((row & 7) << 4));
                const short8 vh = *(const short8*)((const char*)&vbh[cur][0] + off);
                const short8 vl = *(const short8*)((const char*)&vbl[cur][0] + off);
                #pragma unroll
                for (int f = 0; f < 2; ++f) {
                    acc[f][nf] = MFMA(pa[f][0], vh, acc[f][nf]);
                    acc[f][nf] = MFMA(pa[f][0], vl, acc[f][nf]);
                    acc[f][nf] = MFMA(pa[f][1], vh, acc[f][nf]);
                }
            }
        }

        __syncthreads();
    }

    // epilogue: divide by l, split-store
    #pragma unroll
    for (int f = 0; f < 2; ++f) {
        float linv[4];
        #pragma unroll
        for (int j = 0; j < 4; ++j) linv[j] = 1.0f / __shfl(l_st[f], lg*4 + j);
        #pragma unroll
        for (int nf = 0; nf < 4; ++nf) {
            const int c = h*HD + nf*16 + lx;
            #pragma unroll
            for (int j = 0; j < 4; ++j) {
                const size_t tok = (size_t)b*SEQ + qblk + w*32 + f*16 + lg*4 + j;
                const float o = acc[f][nf][j] * linv[j];
                const unsigned short hi = f2bf(o);
                AOh[tok*DIM + c] = hi;
                AOl[tok*DIM + c] = f2bf(o - bf2f(hi));
            }
        }
    }
}

// ---------------------------------------------------------------------------
extern "C" void kernel_launch(void* const* d_in, const int* in_sizes, int n_in,
                              void* d_out, int out_size, void* d_ws, size_t ws_size,
                              hipStream_t stream)
{
    const float* x    = (const float*)d_in[0];
    const float* mask = (const float*)d_in[1];
    const float* fc   = (const float*)d_in[2];
    const float* fs   = (const float*)d_in[3];
    const float* wq   = (const float*)d_in[4];
    const float* bq   = (const float*)d_in[5];
    const float* wk   = (const float*)d_in[6];
    const float* bk   = (const float*)d_in[7];
    const float* wv   = (const float*)d_in[8];
    const float* bv   = (const float*)d_in[9];
    const float* wo   = (const float*)d_in[10];
    float* out = (float*)d_out;

    const size_t MB = 1024*1024;
    char* ws = (char*)d_ws;
    unsigned short* Xh  = (unsigned short*)(ws + 0*MB);
    unsigned short* Xl  = (unsigned short*)(ws + 8*MB);
    unsigned short* WTh = (unsigned short*)(ws + 16*MB);   // 4 planes x 2MB (q,k,v,o)
    unsigned short* WTl = (unsigned short*)(ws + 24*MB);
    unsigned short* Qh  = (unsigned short*)(ws + 32*MB);
    unsigned short* Ql  = (unsigned short*)(ws + 40*MB);
    unsigned short* Kh  = (unsigned short*)(ws + 48*MB);
    unsigned short* Kl  = (unsigned short*)(ws + 56*MB);
    unsigned short* Vth = (unsigned short*)(ws + 64*MB);
    unsigned short* Vtl = (unsigned short*)(ws + 72*MB);
    unsigned short* AOh = Xh;   // reuse after QKV GEMM consumed X planes
    unsigned short* AOl = Xl;

    const size_t WP = (size_t)DIM * DIM;  // weight plane elements

    splitx_kernel<<<(ROWS*DIM)/4/256, 256, 0, stream>>>(x, Xh, Xl);
    splitw_kernel<<<dim3(16, 16, 4), 256, 0, stream>>>(wq, wk, wv, wo, WTh, WTl);

    gemm3_kernel<0><<<dim3(8, 32, 3), 256, 0, stream>>>(
        Xh, Xl,
        WTh, WTl, WTh + WP, WTl + WP, WTh + 2*WP, WTl + 2*WP,
        bq, bk, bv, fc, fs,
        Qh, Ql, Kh, Kl, Vth, Vtl, nullptr);

    attn_kernel<<<dim3(SEQ/256, NH, BATCH), 512, 0, stream>>>(
        Qh, Ql, Kh, Kl, Vth, Vtl, mask, AOh, AOl);

    gemm3_kernel<1><<<dim3(8, 32, 1), 256, 0, stream>>>(
        AOh, AOl,
        WTh + 3*WP, WTl + 3*WP, nullptr, nullptr, nullptr, nullptr,
        nullptr, nullptr, nullptr, fc, fs,
        nullptr, nullptr, nullptr, nullptr, nullptr, nullptr, out);
    (void)in_sizes; (void)n_in; (void)out_size; (void)ws_size;
}

// Round 5
// 355.503 us; speedup vs baseline: 1.2155x; 1.2155x over previous
//
#include <hip/hip_runtime.h>
#include <math.h>
#include <stdint.h>

#define DIM   1024
#define NH    16
#define HD    64
#define BATCH 2
#define SEQ   2048
#define ROWS  (BATCH*SEQ)   // 4096

typedef __attribute__((ext_vector_type(8))) short short8;   // 8 x bf16 (4 VGPR)
typedef __attribute__((ext_vector_type(4))) float f32x4;

// ---- bf16 split helpers (RNE) ----------------------------------------------
__device__ __forceinline__ unsigned short f2bf(float f) {
    union { float f; unsigned u; } x; x.f = f;
    unsigned r = x.u + 0x7FFFu + ((x.u >> 16) & 1u);
    return (unsigned short)(r >> 16);
}
__device__ __forceinline__ float bf2f(unsigned short h) {
    union { unsigned u; float f; } x; x.u = ((unsigned)h) << 16;
    return x.f;
}

#define MFMA(a,b,c) __builtin_amdgcn_mfma_f32_16x16x32_bf16((a),(b),(c),0,0,0)

// async global->LDS, 16B per lane. LDS dest must be linear (base + lane*16).
__device__ __forceinline__ void gl_lds16(const void* g, void* l) {
    __builtin_amdgcn_global_load_lds(
        (const __attribute__((address_space(1))) unsigned int*)g,
        (__attribute__((address_space(3))) unsigned int*)l,
        16, 0, 0);
}

// ---------------------------------------------------------------------------
// split x -> Xh, Xl bf16 planes
// ---------------------------------------------------------------------------
__global__ __launch_bounds__(256) void splitx_kernel(
    const float* __restrict__ x, unsigned short* __restrict__ xh, unsigned short* __restrict__ xl)
{
    const size_t i = ((size_t)blockIdx.x * 256 + threadIdx.x) * 4;
    const float4 v = *(const float4*)&x[i];
    ushort4 h, l;
    h.x = f2bf(v.x); l.x = f2bf(v.x - bf2f(h.x));
    h.y = f2bf(v.y); l.y = f2bf(v.y - bf2f(h.y));
    h.z = f2bf(v.z); l.z = f2bf(v.z - bf2f(h.z));
    h.w = f2bf(v.w); l.w = f2bf(v.w - bf2f(h.w));
    *(ushort4*)&xh[i] = h;
    *(ushort4*)&xl[i] = l;
}

// ---------------------------------------------------------------------------
// transpose + split the four 1024x1024 weights: WT[n][k] hi/lo bf16
// ---------------------------------------------------------------------------
__global__ __launch_bounds__(256) void splitw_kernel(
    const float* __restrict__ w0, const float* __restrict__ w1,
    const float* __restrict__ w2, const float* __restrict__ w3,
    unsigned short* __restrict__ wth, unsigned short* __restrict__ wtl)
{
    __shared__ float tile[64][68];
    const int z = blockIdx.z;
    const float* W = (z == 0) ? w0 : (z == 1) ? w1 : (z == 2) ? w2 : w3;
    unsigned short* th = wth + (size_t)z * DIM * DIM;
    unsigned short* tl = wtl + (size_t)z * DIM * DIM;
    const int k0 = blockIdx.y * 64, n0 = blockIdx.x * 64;
    const int tr = threadIdx.x >> 4, tc = (threadIdx.x & 15) * 4;
    #pragma unroll
    for (int p = 0; p < 4; ++p) {
        const float4 v = *(const float4*)&W[(size_t)(k0 + tr + p*16) * DIM + n0 + tc];
        *(float4*)&tile[tr + p*16][tc] = v;
    }
    __syncthreads();
    #pragma unroll
    for (int p = 0; p < 4; ++p) {
        const int n = tr + p*16;
        ushort4 hv, lv;
        float v0 = tile[tc+0][n], v1 = tile[tc+1][n], v2 = tile[tc+2][n], v3 = tile[tc+3][n];
        hv.x = f2bf(v0); lv.x = f2bf(v0 - bf2f(hv.x));
        hv.y = f2bf(v1); lv.y = f2bf(v1 - bf2f(hv.y));
        hv.z = f2bf(v2); lv.z = f2bf(v2 - bf2f(hv.z));
        hv.w = f2bf(v3); lv.w = f2bf(v3 - bf2f(hv.w));
        *(ushort4*)&th[(size_t)(n0 + n) * DIM + k0 + tc] = hv;
        *(ushort4*)&tl[(size_t)(n0 + n) * DIM + k0 + tc] = lv;
    }
}

// ---------------------------------------------------------------------------
// split-bf16 3-term MFMA GEMM (R2 structure: reg-staged, 32 KB LDS, ~3 blk/CU)
// ---------------------------------------------------------------------------
template<int MODE>
__global__ __launch_bounds__(256, 2) void gemm3_kernel(
    const unsigned short* __restrict__ Ah, const unsigned short* __restrict__ Al,
    const unsigned short* __restrict__ Wh0, const unsigned short* __restrict__ Wl0,
    const unsigned short* __restrict__ Wh1, const unsigned short* __restrict__ Wl1,
    const unsigned short* __restrict__ Wh2, const unsigned short* __restrict__ Wl2,
    const float* __restrict__ b0, const float* __restrict__ b1, const float* __restrict__ b2,
    const float* __restrict__ fc, const float* __restrict__ fs,
    unsigned short* __restrict__ q_h, unsigned short* __restrict__ q_l,
    unsigned short* __restrict__ k_h, unsigned short* __restrict__ k_l,
    unsigned short* __restrict__ vt_h, unsigned short* __restrict__ vt_l,
    float* __restrict__ outf)
{
    __shared__ __align__(16) unsigned short lah[128*32], lal[128*32];
    __shared__ __align__(16) unsigned short lbh[128*32], lbl[128*32];

    const int tid = threadIdx.x;
    const int lane = tid & 63;
    const int lx = lane & 15, lg = lane >> 4;
    const int wv = tid >> 6, wm = wv >> 1, wn = wv & 1;
    const int n0 = blockIdx.x * 128, m0 = blockIdx.y * 128;
    const int z = (MODE == 0) ? blockIdx.z : 3;

    const unsigned short *Wh, *Wl;
    const float* bias;
    if (MODE == 0) {
        Wh = (z == 0) ? Wh0 : (z == 1) ? Wh1 : Wh2;
        Wl = (z == 0) ? Wl0 : (z == 1) ? Wl1 : Wl2;
        bias = (z == 0) ? b0 : (z == 1) ? b1 : b2;
    } else { Wh = Wh0; Wl = Wl0; bias = nullptr; }

    const int sr  = tid >> 2;          // staging row 0..63 (and +64)
    const int scb = (tid & 3) << 4;    // byte col within 64B row

    f32x4 acc[4][4] = {};
    uint4 ra0, ra1, rl0, rl1, rb0, rb1, rb2, rb3;

    auto loadA = [&](int k0i) {
        const size_t a0 = ((size_t)(m0 + sr)      * DIM + k0i) * 2 + scb;
        const size_t a1 = ((size_t)(m0 + sr + 64) * DIM + k0i) * 2 + scb;
        ra0 = *(const uint4*)((const char*)Ah + a0);
        ra1 = *(const uint4*)((const char*)Ah + a1);
        rl0 = *(const uint4*)((const char*)Al + a0);
        rl1 = *(const uint4*)((const char*)Al + a1);
        const size_t bb0 = ((size_t)(n0 + sr)      * DIM + k0i) * 2 + scb;
        const size_t bb1 = ((size_t)(n0 + sr + 64) * DIM + k0i) * 2 + scb;
        rb0 = *(const uint4*)((const char*)Wh + bb0);
        rb1 = *(const uint4*)((const char*)Wh + bb1);
        rb2 = *(const uint4*)((const char*)Wl + bb0);
        rb3 = *(const uint4*)((const char*)Wl + bb1);
    };

    loadA(0);
    for (int k0i = 0; k0i < DIM; k0i += 32) {
        __syncthreads();
        {
            const int o0 = sr*64 + scb, o1 = (sr + 64)*64 + scb;
            *(uint4*)((char*)lah + o0) = ra0; *(uint4*)((char*)lah + o1) = ra1;
            *(uint4*)((char*)lal + o0) = rl0; *(uint4*)((char*)lal + o1) = rl1;
            *(uint4*)((char*)lbh + o0) = rb0; *(uint4*)((char*)lbh + o1) = rb1;
            *(uint4*)((char*)lbl + o0) = rb2; *(uint4*)((char*)lbl + o1) = rb3;
        }
        __syncthreads();
        if (k0i + 32 < DIM) loadA(k0i + 32);

        short8 afh[4], afl[4], bfh[4], bfl[4];
        #pragma unroll
        for (int i = 0; i < 4; ++i) {
            const int ar = wm*64 + i*16 + lx;
            afh[i] = *(const short8*)((const char*)lah + ar*64 + lg*16);
            afl[i] = *(const short8*)((const char*)lal + ar*64 + lg*16);
            const int br = wn*64 + i*16 + lx;
            bfh[i] = *(const short8*)((const char*)lbh + br*64 + lg*16);
            bfl[i] = *(const short8*)((const char*)lbl + br*64 + lg*16);
        }
        #pragma unroll
        for (int i = 0; i < 4; ++i)
        #pragma unroll
        for (int jn = 0; jn < 4; ++jn) {
            acc[i][jn] = MFMA(afh[i], bfh[jn], acc[i][jn]);
            acc[i][jn] = MFMA(afh[i], bfl[jn], acc[i][jn]);
            acc[i][jn] = MFMA(afl[i], bfh[jn], acc[i][jn]);
        }
    }

    // epilogue
    #pragma unroll
    for (int i = 0; i < 4; ++i) {
        const int tokbase = m0 + wm*64 + i*16 + lg*4;
        #pragma unroll
        for (int jn = 0; jn < 4; ++jn) {
            const int c = n0 + wn*64 + jn*16 + lx;
            float bv = (MODE == 0) ? bias[c] : 0.f;
            float vj[4];
            #pragma unroll
            for (int j = 0; j < 4; ++j) vj[j] = acc[i][jn][j] + bv;
            if (MODE == 0 && z < 2) {
                const int i0 = (c & 63) >> 1;
                #pragma unroll
                for (int j = 0; j < 4; ++j) {
                    const int s = (tokbase + j) & (SEQ - 1);
                    const float cv = fc[s*32 + i0], sv = fs[s*32 + i0];
                    const float pv = __shfl_xor(vj[j], 1);
                    vj[j] = (c & 1) ? (pv*sv + vj[j]*cv) : (vj[j]*cv - pv*sv);
                }
            }
            if (MODE == 1) {
                #pragma unroll
                for (int j = 0; j < 4; ++j)
                    outf[(size_t)(tokbase + j) * DIM + c] = vj[j];
            } else if (z < 2) {
                unsigned short* oh = z ? k_h : q_h;
                unsigned short* ol = z ? k_l : q_l;
                #pragma unroll
                for (int j = 0; j < 4; ++j) {
                    const unsigned short hi = f2bf(vj[j]);
                    oh[(size_t)(tokbase + j) * DIM + c] = hi;
                    ol[(size_t)(tokbase + j) * DIM + c] = f2bf(vj[j] - bf2f(hi));
                }
            } else {
                const int bb = tokbase >> 11, s0 = tokbase & (SEQ - 1);
                const int hh = c >> 6, d = c & 63;
                const size_t vb = ((size_t)(bb*NH + hh) * HD + d) * SEQ + s0;
                ushort4 hv, lv;
                #pragma unroll
                for (int j = 0; j < 4; ++j) {
                    const unsigned short hi = f2bf(vj[j]);
                    ((unsigned short*)&hv)[j] = hi;
                    ((unsigned short*)&lv)[j] = f2bf(vj[j] - bf2f(hi));
                }
                *(ushort4*)&vt_h[vb] = hv;
                *(ushort4*)&vt_l[vb] = lv;
            }
        }
    }
}

// ---------------------------------------------------------------------------
// MFMA flash attention. 256 thr = 4 waves, Q-tile 128 (32 q/wave, 2 frags),
// K/V 64-row tiles double-buffered (swizzled), P hi-only in wave-private LDS
// (ks-split). 72 KB LDS -> 2 independent blocks/CU (barrier-decoupled).
// grid (SEQ/128, NH, BATCH) = 512 blocks.
// ---------------------------------------------------------------------------
__global__ __launch_bounds__(256, 2) void attn_kernel(
    const unsigned short* __restrict__ Qh, const unsigned short* __restrict__ Ql,
    const unsigned short* __restrict__ Kh, const unsigned short* __restrict__ Kl,
    const unsigned short* __restrict__ Vth, const unsigned short* __restrict__ Vtl,
    const float* __restrict__ mask,
    unsigned short* __restrict__ AOh, unsigned short* __restrict__ AOl)
{
    __shared__ __align__(16) unsigned short kbh[2][64*64], kbl[2][64*64];
    __shared__ __align__(16) unsigned short vbh[2][64*64], vbl[2][64*64];
    __shared__ __align__(16) unsigned short pb[4][2][16*32];   // P hi, ks-half

    const int tid = threadIdx.x;
    const int w = tid >> 6, lane = tid & 63;
    const int lx = lane & 15, lg = lane >> 4;
    const int qblk = blockIdx.x * 128;
    const int h = blockIdx.y, b = blockIdx.z;

    const int qrow0 = qblk + w*32 + lx;          // frag 0 softmax row
    const int qrow1 = qrow0 + 16;                // frag 1

    short8 qf[2][2][2];                          // [frag][plane][ks]
    {
        const size_t base0 = ((size_t)b*SEQ + qrow0) * DIM + h*HD + lg*8;
        const size_t base1 = ((size_t)b*SEQ + qrow1) * DIM + h*HD + lg*8;
        qf[0][0][0] = *(const short8*)&Qh[base0];  qf[0][0][1] = *(const short8*)&Qh[base0 + 32];
        qf[0][1][0] = *(const short8*)&Ql[base0];  qf[0][1][1] = *(const short8*)&Ql[base0 + 32];
        qf[1][0][0] = *(const short8*)&Qh[base1];  qf[1][0][1] = *(const short8*)&Qh[base1 + 32];
        qf[1][1][0] = *(const short8*)&Ql[base1];  qf[1][1][1] = *(const short8*)&Ql[base1 + 32];
    }

    float m_st[2] = {-INFINITY, -INFINITY}, l_st[2] = {0.f, 0.f};
    f32x4 acc[2][4] = {};

    // staging: 256 threads, one 64x64 bf16 plane = 8KB = 2 gl_lds16 rounds
    const int sr  = tid >> 3;                             // row 0..31
    const int gco = ((tid & 7) * 16) ^ ((sr & 7) << 4);   // pre-swizzled byte col
    const int ldso = tid * 16;                            // linear LDS dest (4KB)

    const char* khs = (const char*)Kh + ((size_t)b*SEQ + sr) * DIM * 2 + h*128 + gco;
    const char* kls = (const char*)Kl + ((size_t)b*SEQ + sr) * DIM * 2 + h*128 + gco;
    const char* vhs = (const char*)Vth + ((size_t)(b*NH + h)*HD + sr) * SEQ * 2 + gco;
    const char* vls = (const char*)Vtl + ((size_t)(b*NH + h)*HD + sr) * SEQ * 2 + gco;
    const size_t krs = (size_t)32 * DIM * 2;   // +32 K-rows
    const size_t vrs = (size_t)32 * SEQ * 2;   // +32 V-d-rows

    auto STAGE = [&](int t, int buf) {
        const size_t ko = (size_t)t * 64 * DIM * 2;
        const size_t vo = (size_t)t * 128;
        gl_lds16(khs + ko,       (char*)&kbh[buf][0] + ldso);
        gl_lds16(khs + ko + krs, (char*)&kbh[buf][0] + ldso + 4096);
        gl_lds16(kls + ko,       (char*)&kbl[buf][0] + ldso);
        gl_lds16(kls + ko + krs, (char*)&kbl[buf][0] + ldso + 4096);
        gl_lds16(vhs + vo,       (char*)&vbh[buf][0] + ldso);
        gl_lds16(vhs + vo + vrs, (char*)&vbh[buf][0] + ldso + 4096);
        gl_lds16(vls + vo,       (char*)&vbl[buf][0] + ldso);
        gl_lds16(vls + vo + vrs, (char*)&vbl[buf][0] + ldso + 4096);
    };

    STAGE(0, 0);
    __syncthreads();

    const float* mrow0 = mask + (size_t)qrow0 * SEQ;
    const float* mrow1 = mask + (size_t)qrow1 * SEQ;

    for (int t = 0; t < SEQ/64; ++t) {
        const int cur = t & 1;
        if (t + 1 < SEQ/64) STAGE(t + 1, cur ^ 1);

        // mask prefetch (k = 16mf + 4lg + j)
        float4 mk[2][4];
        #pragma unroll
        for (int mf = 0; mf < 4; ++mf) {
            mk[0][mf] = *(const float4*)&mrow0[t*64 + mf*16 + lg*4];
            mk[1][mf] = *(const float4*)&mrow1[t*64 + mf*16 + lg*4];
        }

        // --- S^T = K . Q^T (3-term), both q-frags share every K read ---
        f32x4 st[2][4] = {};
        __builtin_amdgcn_s_setprio(1);
        #pragma unroll
        for (int ks = 0; ks < 2; ++ks) {
            #pragma unroll
            for (int mf = 0; mf < 4; ++mf) {
                const int row = mf*16 + lx;
                const int off = row*128 + ((ks*64 + lg*16) ^ ((row & 7) << 4));
                const short8 akh = *(const short8*)((const char*)&kbh[cur][0] + off);
                const short8 akl = *(const short8*)((const char*)&kbl[cur][0] + off);
                #pragma unroll
                for (int f = 0; f < 2; ++f) {
                    st[f][mf] = MFMA(akh, qf[f][0][ks], st[f][mf]);
                    st[f][mf] = MFMA(akh, qf[f][1][ks], st[f][mf]);
                    st[f][mf] = MFMA(akl, qf[f][0][ks], st[f][mf]);
                }
            }
        }
        __builtin_amdgcn_s_setprio(0);

        // --- online softmax per frag (lane owns q-col lx of its frag) ---
        unsigned pw[2][4][2];
        #pragma unroll
        for (int f = 0; f < 2; ++f) {
            float p[4][4];
            float mx = -INFINITY;
            #pragma unroll
            for (int mf = 0; mf < 4; ++mf) {
                p[mf][0] = st[f][mf][0]*0.125f + mk[f][mf].x;
                p[mf][1] = st[f][mf][1]*0.125f + mk[f][mf].y;
                p[mf][2] = st[f][mf][2]*0.125f + mk[f][mf].z;
                p[mf][3] = st[f][mf][3]*0.125f + mk[f][mf].w;
                mx = fmaxf(mx, fmaxf(fmaxf(p[mf][0], p[mf][1]), fmaxf(p[mf][2], p[mf][3])));
            }
            mx = fmaxf(mx, __shfl_xor(mx, 16));
            mx = fmaxf(mx, __shfl_xor(mx, 32));
            const float mnew = fmaxf(m_st[f], mx);
            const float scl = __expf(m_st[f] - mnew);
            m_st[f] = mnew;

            float ps = 0.f;
            #pragma unroll
            for (int mf = 0; mf < 4; ++mf) {
                const float e0 = __expf(p[mf][0] - mnew), e1 = __expf(p[mf][1] - mnew);
                const float e2 = __expf(p[mf][2] - mnew), e3 = __expf(p[mf][3] - mnew);
                ps += (e0 + e1) + (e2 + e3);
                pw[f][mf][0] = (unsigned)f2bf(e0) | ((unsigned)f2bf(e1) << 16);
                pw[f][mf][1] = (unsigned)f2bf(e2) | ((unsigned)f2bf(e3) << 16);
            }
            ps += __shfl_xor(ps, 16);
            ps += __shfl_xor(ps, 32);
            l_st[f] = l_st[f]*scl + ps;

            float fj[4];
            #pragma unroll
            for (int j = 0; j < 4; ++j) fj[j] = __shfl(scl, lg*4 + j);
            #pragma unroll
            for (int nf = 0; nf < 4; ++nf)
                #pragma unroll
                for (int j = 0; j < 4; ++j) acc[f][nf][j] *= fj[j];
        }

        // --- O += P . V (P hi x V hi/lo), ks-split through wave-private LDS ---
        #pragma unroll
        for (int ks = 0; ks < 2; ++ks) {
            // write this ks-half of P (k_local = (mf&1)*16 + lg*4 + j)
            #pragma unroll
            for (int f = 0; f < 2; ++f)
                #pragma unroll
                for (int mm = 0; mm < 2; ++mm) {
                    const int off = lx*64 + ((mm*32 + lg*8) ^ ((lx & 3) << 4));
                    *(uint2*)((char*)&pb[w][f][0] + off) =
                        make_uint2(pw[f][ks*2 + mm][0], pw[f][ks*2 + mm][1]);
                }
            short8 pa[2];
            #pragma unroll
            for (int f = 0; f < 2; ++f) {
                const int poff = lx*64 + ((lg*16) ^ ((lx & 3) << 4));
                pa[f] = *(const short8*)((const char*)&pb[w][f][0] + poff);
            }
            __builtin_amdgcn_s_setprio(1);
            #pragma unroll
            for (int nf = 0; nf < 4; ++nf) {
                const int row = nf*16 + lx;
                const int off = row*128 + ((ks*64 + lg*16) ^ ((row & 7) << 4));
                const short8 vh = *(const short8*)((const char*)&vbh[cur][0] + off);
                const short8 vl = *(const short8*)((const char*)&vbl[cur][0] + off);
                #pragma unroll
                for (int f = 0; f < 2; ++f) {
                    acc[f][nf] = MFMA(pa[f], vh, acc[f][nf]);
                    acc[f][nf] = MFMA(pa[f], vl, acc[f][nf]);
                }
            }
            __builtin_amdgcn_s_setprio(0);
        }

        __syncthreads();
    }

    // epilogue: divide by l, split-store
    #pragma unroll
    for (int f = 0; f < 2; ++f) {
        float linv[4];
        #pragma unroll
        for (int j = 0; j < 4; ++j) linv[j] = 1.0f / __shfl(l_st[f], lg*4 + j);
        #pragma unroll
        for (int nf = 0; nf < 4; ++nf) {
            const int c = h*HD + nf*16 + lx;
            #pragma unroll
            for (int j = 0; j < 4; ++j) {
                const size_t tok = (size_t)b*SEQ + qblk + w*32 + f*16 + lg*4 + j;
                const float o = acc[f][nf][j] * linv[j];
                const unsigned short hi = f2bf(o);
                AOh[tok*DIM + c] = hi;
                AOl[tok*DIM + c] = f2bf(o - bf2f(hi));
            }
        }
    }
}

// ---------------------------------------------------------------------------
extern "C" void kernel_launch(void* const* d_in, const int* in_sizes, int n_in,
                              void* d_out, int out_size, void* d_ws, size_t ws_size,
                              hipStream_t stream)
{
    const float* x    = (const float*)d_in[0];
    const float* mask = (const float*)d_in[1];
    const float* fc   = (const float*)d_in[2];
    const float* fs   = (const float*)d_in[3];
    const float* wq   = (const float*)d_in[4];
    const float* bq   = (const float*)d_in[5];
    const float* wk   = (const float*)d_in[6];
    const float* bk   = (const float*)d_in[7];
    const float* wv   = (const float*)d_in[8];
    const float* bv   = (const float*)d_in[9];
    const float* wo   = (const float*)d_in[10];
    float* out = (float*)d_out;

    const size_t MB = 1024*1024;
    char* ws = (char*)d_ws;
    unsigned short* Xh  = (unsigned short*)(ws + 0*MB);
    unsigned short* Xl  = (unsigned short*)(ws + 8*MB);
    unsigned short* WTh = (unsigned short*)(ws + 16*MB);   // 4 planes x 2MB (q,k,v,o)
    unsigned short* WTl = (unsigned short*)(ws + 24*MB);
    unsigned short* Qh  = (unsigned short*)(ws + 32*MB);
    unsigned short* Ql  = (unsigned short*)(ws + 40*MB);
    unsigned short* Kh  = (unsigned short*)(ws + 48*MB);
    unsigned short* Kl  = (unsigned short*)(ws + 56*MB);
    unsigned short* Vth = (unsigned short*)(ws + 64*MB);
    unsigned short* Vtl = (unsigned short*)(ws + 72*MB);
    unsigned short* AOh = Xh;   // reuse after QKV GEMM consumed X planes
    unsigned short* AOl = Xl;

    const size_t WP = (size_t)DIM * DIM;  // weight plane elements

    splitx_kernel<<<(ROWS*DIM)/4/256, 256, 0, stream>>>(x, Xh, Xl);
    splitw_kernel<<<dim3(16, 16, 4), 256, 0, stream>>>(wq, wk, wv, wo, WTh, WTl);

    gemm3_kernel<0><<<dim3(8, 32, 3), 256, 0, stream>>>(
        Xh, Xl,
        WTh, WTl, WTh + WP, WTl + WP, WTh + 2*WP, WTl + 2*WP,
        bq, bk, bv, fc, fs,
        Qh, Ql, Kh, Kl, Vth, Vtl, nullptr);

    attn_kernel<<<dim3(SEQ/128, NH, BATCH), 256, 0, stream>>>(
        Qh, Ql, Kh, Kl, Vth, Vtl, mask, AOh, AOl);

    gemm3_kernel<1><<<dim3(8, 32, 1), 256, 0, stream>>>(
        AOh, AOl,
        WTh + 3*WP, WTl + 3*WP, nullptr, nullptr, nullptr, nullptr,
        nullptr, nullptr, nullptr, fc, fs,
        nullptr, nullptr, nullptr, nullptr, nullptr, nullptr, out);
    (void)in_sizes; (void)n_in; (void)out_size; (void)ws_size;
}

// Round 6
// 304.348 us; speedup vs baseline: 1.4198x; 1.1681x over previous
//
#include <hip/hip_runtime.h>
#include <hip/hip_fp16.h>
#include <math.h>
#include <stdint.h>

#define DIM   1024
#define NH    16
#define HD    64
#define BATCH 2
#define SEQ   2048
#define ROWS  (BATCH*SEQ)   // 4096

typedef __attribute__((ext_vector_type(8))) short short8;   // 8 x fp16 (4 VGPR)
typedef __attribute__((ext_vector_type(4))) float f32x4;

// ---- fp16 helpers (RNE) -----------------------------------------------------
__device__ __forceinline__ unsigned short f2h(float f) {
    __half h = __float2half(f);
    return *(unsigned short*)&h;
}
__device__ __forceinline__ float h2f(unsigned short u) {
    __half h = *(__half*)&u;
    return __half2float(h);
}

#define MFMA16(a,b,c) __builtin_amdgcn_mfma_f32_16x16x32_f16((a),(b),(c),0,0,0)

// async global->LDS, 16B per lane. LDS dest must be linear (base + lane*16).
__device__ __forceinline__ void gl_lds16(const void* g, void* l) {
    __builtin_amdgcn_global_load_lds(
        (const __attribute__((address_space(1))) unsigned int*)g,
        (__attribute__((address_space(3))) unsigned int*)l,
        16, 0, 0);
}

// ---------------------------------------------------------------------------
// split x -> Xh, Xl fp16 planes (2-term: x = h + l, |l| <= 2^-11 |x|)
// ---------------------------------------------------------------------------
__global__ __launch_bounds__(256) void splitx_kernel(
    const float* __restrict__ x, unsigned short* __restrict__ xh, unsigned short* __restrict__ xl)
{
    const size_t i = ((size_t)blockIdx.x * 256 + threadIdx.x) * 4;
    const float4 v = *(const float4*)&x[i];
    ushort4 h, l;
    h.x = f2h(v.x); l.x = f2h(v.x - h2f(h.x));
    h.y = f2h(v.y); l.y = f2h(v.y - h2f(h.y));
    h.z = f2h(v.z); l.z = f2h(v.z - h2f(h.z));
    h.w = f2h(v.w); l.w = f2h(v.w - h2f(h.w));
    *(ushort4*)&xh[i] = h;
    *(ushort4*)&xl[i] = l;
}

// ---------------------------------------------------------------------------
// transpose the four 1024x1024 weights -> WT[n][k] single fp16 plane
// grid (16,16,4)
// ---------------------------------------------------------------------------
__global__ __launch_bounds__(256) void splitw_kernel(
    const float* __restrict__ w0, const float* __restrict__ w1,
    const float* __restrict__ w2, const float* __restrict__ w3,
    unsigned short* __restrict__ wt)
{
    __shared__ float tile[64][68];
    const int z = blockIdx.z;
    const float* W = (z == 0) ? w0 : (z == 1) ? w1 : (z == 2) ? w2 : w3;
    unsigned short* th = wt + (size_t)z * DIM * DIM;
    const int k0 = blockIdx.y * 64, n0 = blockIdx.x * 64;
    const int tr = threadIdx.x >> 4, tc = (threadIdx.x & 15) * 4;
    #pragma unroll
    for (int p = 0; p < 4; ++p) {
        const float4 v = *(const float4*)&W[(size_t)(k0 + tr + p*16) * DIM + n0 + tc];
        *(float4*)&tile[tr + p*16][tc] = v;
    }
    __syncthreads();
    #pragma unroll
    for (int p = 0; p < 4; ++p) {
        const int n = tr + p*16;
        ushort4 hv;
        hv.x = f2h(tile[tc+0][n]);
        hv.y = f2h(tile[tc+1][n]);
        hv.z = f2h(tile[tc+2][n]);
        hv.w = f2h(tile[tc+3][n]);
        *(ushort4*)&th[(size_t)(n0 + n) * DIM + k0 + tc] = hv;
    }
}

// ---------------------------------------------------------------------------
// fp16 2-term MFMA GEMM: C = A @ W (+bias)(+RoPE). A fp16 hi/lo, W fp16 single
// (transposed, TN). 128x128 tile, BK=32, reg-staged, 24 KB LDS (~3 blk/CU).
// MODE 0: QKV (z selects)   MODE 1: out-proj (fp32 store)
// ---------------------------------------------------------------------------
template<int MODE>
__global__ __launch_bounds__(256, 2) void gemm3_kernel(
    const unsigned short* __restrict__ Ah, const unsigned short* __restrict__ Al,
    const unsigned short* __restrict__ W0, const unsigned short* __restrict__ W1,
    const unsigned short* __restrict__ W2,
    const float* __restrict__ b0, const float* __restrict__ b1, const float* __restrict__ b2,
    const float* __restrict__ fc, const float* __restrict__ fs,
    unsigned short* __restrict__ q_h, unsigned short* __restrict__ q_l,
    unsigned short* __restrict__ k_h, unsigned short* __restrict__ vt_h,
    float* __restrict__ outf)
{
    __shared__ __align__(16) unsigned short lah[128*32], lal[128*32], lbh[128*32];

    const int tid = threadIdx.x;
    const int lane = tid & 63;
    const int lx = lane & 15, lg = lane >> 4;
    const int wv = tid >> 6, wm = wv >> 1, wn = wv & 1;
    const int n0 = blockIdx.x * 128, m0 = blockIdx.y * 128;
    const int z = (MODE == 0) ? blockIdx.z : 3;

    const unsigned short* Wh;
    const float* bias;
    if (MODE == 0) {
        Wh = (z == 0) ? W0 : (z == 1) ? W1 : W2;
        bias = (z == 0) ? b0 : (z == 1) ? b1 : b2;
    } else { Wh = W0; bias = nullptr; }

    const int sr  = tid >> 2;          // staging row 0..63 (and +64)
    const int scb = (tid & 3) << 4;    // byte col within 64B row

    f32x4 acc[4][4] = {};
    uint4 ra0, ra1, rl0, rl1, rb0, rb1;

    auto loadA = [&](int k0i) {
        const size_t a0 = ((size_t)(m0 + sr)      * DIM + k0i) * 2 + scb;
        const size_t a1 = ((size_t)(m0 + sr + 64) * DIM + k0i) * 2 + scb;
        ra0 = *(const uint4*)((const char*)Ah + a0);
        ra1 = *(const uint4*)((const char*)Ah + a1);
        rl0 = *(const uint4*)((const char*)Al + a0);
        rl1 = *(const uint4*)((const char*)Al + a1);
        const size_t bb0 = ((size_t)(n0 + sr)      * DIM + k0i) * 2 + scb;
        const size_t bb1 = ((size_t)(n0 + sr + 64) * DIM + k0i) * 2 + scb;
        rb0 = *(const uint4*)((const char*)Wh + bb0);
        rb1 = *(const uint4*)((const char*)Wh + bb1);
    };

    loadA(0);
    for (int k0i = 0; k0i < DIM; k0i += 32) {
        __syncthreads();
        {
            const int o0 = sr*64 + scb, o1 = (sr + 64)*64 + scb;
            *(uint4*)((char*)lah + o0) = ra0; *(uint4*)((char*)lah + o1) = ra1;
            *(uint4*)((char*)lal + o0) = rl0; *(uint4*)((char*)lal + o1) = rl1;
            *(uint4*)((char*)lbh + o0) = rb0; *(uint4*)((char*)lbh + o1) = rb1;
        }
        __syncthreads();
        if (k0i + 32 < DIM) loadA(k0i + 32);

        short8 afh[4], afl[4], bfh[4];
        #pragma unroll
        for (int i = 0; i < 4; ++i) {
            const int ar = wm*64 + i*16 + lx;
            afh[i] = *(const short8*)((const char*)lah + ar*64 + lg*16);
            afl[i] = *(const short8*)((const char*)lal + ar*64 + lg*16);
            const int br = wn*64 + i*16 + lx;
            bfh[i] = *(const short8*)((const char*)lbh + br*64 + lg*16);
        }
        #pragma unroll
        for (int i = 0; i < 4; ++i)
        #pragma unroll
        for (int jn = 0; jn < 4; ++jn) {
            acc[i][jn] = MFMA16(afh[i], bfh[jn], acc[i][jn]);
            acc[i][jn] = MFMA16(afl[i], bfh[jn], acc[i][jn]);
        }
    }

    // epilogue
    #pragma unroll
    for (int i = 0; i < 4; ++i) {
        const int tokbase = m0 + wm*64 + i*16 + lg*4;
        #pragma unroll
        for (int jn = 0; jn < 4; ++jn) {
            const int c = n0 + wn*64 + jn*16 + lx;
            float bv = (MODE == 0) ? bias[c] : 0.f;
            float vj[4];
            #pragma unroll
            for (int j = 0; j < 4; ++j) vj[j] = acc[i][jn][j] + bv;
            if (MODE == 0 && z < 2) {
                const int i0 = (c & 63) >> 1;
                #pragma unroll
                for (int j = 0; j < 4; ++j) {
                    const int s = (tokbase + j) & (SEQ - 1);
                    const float cv = fc[s*32 + i0], sv = fs[s*32 + i0];
                    const float pv = __shfl_xor(vj[j], 1);
                    vj[j] = (c & 1) ? (pv*sv + vj[j]*cv) : (vj[j]*cv - pv*sv);
                }
            }
            if (MODE == 1) {
                #pragma unroll
                for (int j = 0; j < 4; ++j)
                    outf[(size_t)(tokbase + j) * DIM + c] = vj[j];
            } else if (z == 0) {        // Q: fp16 hi + lo residual
                #pragma unroll
                for (int j = 0; j < 4; ++j) {
                    const unsigned short hi = f2h(vj[j]);
                    q_h[(size_t)(tokbase + j) * DIM + c] = hi;
                    q_l[(size_t)(tokbase + j) * DIM + c] = f2h(vj[j] - h2f(hi));
                }
            } else if (z == 1) {        // K: fp16 single
                #pragma unroll
                for (int j = 0; j < 4; ++j)
                    k_h[(size_t)(tokbase + j) * DIM + c] = f2h(vj[j]);
            } else {                    // V: fp16 single, stored transposed [b][h][d][s]
                const int bb = tokbase >> 11, s0 = tokbase & (SEQ - 1);
                const int hh = c >> 6, d = c & 63;
                const size_t vb = ((size_t)(bb*NH + hh) * HD + d) * SEQ + s0;
                ushort4 hv;
                hv.x = f2h(vj[0]); hv.y = f2h(vj[1]); hv.z = f2h(vj[2]); hv.w = f2h(vj[3]);
                *(ushort4*)&vt_h[vb] = hv;
            }
        }
    }
}

// ---------------------------------------------------------------------------
// fp16 MFMA flash attention. 128 thr = 2 waves, 32 q/wave (2 frags), Q-tile 64.
// K/V single-fp16 64-row tiles double-buffered (3-bit XOR swizzle), Q hi/lo
// 2-term QK, P fp16 1-term PV, defer-max (THR=8). 36 KB LDS -> 4 blocks/CU,
// grid (SEQ/64, NH, BATCH) = 1024 blocks (4 independent barrier domains/CU).
// ---------------------------------------------------------------------------
__global__ __launch_bounds__(128, 2) void attn_kernel(
    const unsigned short* __restrict__ Qh, const unsigned short* __restrict__ Ql,
    const unsigned short* __restrict__ Kh, const unsigned short* __restrict__ Vth,
    const float* __restrict__ mask,
    unsigned short* __restrict__ AOh, unsigned short* __restrict__ AOl)
{
    __shared__ __align__(16) unsigned short kb[2][64*64], vb[2][64*64];
    __shared__ __align__(16) unsigned short pb[2][2][16*32];   // P fp16, ks-half

    const int tid = threadIdx.x;
    const int w = tid >> 6, lane = tid & 63;
    const int lx = lane & 15, lg = lane >> 4;
    const int qblk = blockIdx.x * 64;
    const int h = blockIdx.y, b = blockIdx.z;

    const int qrow0 = qblk + w*32 + lx;          // frag 0 softmax row
    const int qrow1 = qrow0 + 16;                // frag 1

    short8 qf[2][2][2];                          // [frag][hi/lo][ks]
    {
        const size_t base0 = ((size_t)b*SEQ + qrow0) * DIM + h*HD + lg*8;
        const size_t base1 = ((size_t)b*SEQ + qrow1) * DIM + h*HD + lg*8;
        qf[0][0][0] = *(const short8*)&Qh[base0];  qf[0][0][1] = *(const short8*)&Qh[base0 + 32];
        qf[0][1][0] = *(const short8*)&Ql[base0];  qf[0][1][1] = *(const short8*)&Ql[base0 + 32];
        qf[1][0][0] = *(const short8*)&Qh[base1];  qf[1][0][1] = *(const short8*)&Qh[base1 + 32];
        qf[1][1][0] = *(const short8*)&Ql[base1];  qf[1][1][1] = *(const short8*)&Ql[base1 + 32];
    }

    float m_st[2] = {-INFINITY, -INFINITY}, l_st[2] = {0.f, 0.f};
    f32x4 acc[2][4] = {};

    // staging: 128 threads, 2KB per shot, 4 shots per 8KB plane
    const int sr  = tid >> 3;                             // row 0..15
    const int gco = ((tid & 7) * 16) ^ ((sr & 7) << 4);   // pre-swizzled byte col
    const int ldso = tid * 16;                            // linear LDS dest (2KB)

    const char* khs = (const char*)Kh + ((size_t)b*SEQ + sr) * DIM * 2 + h*128 + gco;
    const char* vhs = (const char*)Vth + ((size_t)(b*NH + h)*HD + sr) * SEQ * 2 + gco;
    const size_t krs = (size_t)16 * DIM * 2;   // +16 K-rows
    const size_t vrs = (size_t)16 * SEQ * 2;   // +16 V-d-rows

    auto STAGE = [&](int t, int buf) {
        const size_t ko = (size_t)t * 64 * DIM * 2;
        const size_t vo = (size_t)t * 128;
        #pragma unroll
        for (int s4 = 0; s4 < 4; ++s4) {
            gl_lds16(khs + ko + s4*krs, (char*)&kb[buf][0] + ldso + s4*2048);
            gl_lds16(vhs + vo + s4*vrs, (char*)&vb[buf][0] + ldso + s4*2048);
        }
    };

    STAGE(0, 0);
    __syncthreads();

    const float* mrow0 = mask + (size_t)qrow0 * SEQ;
    const float* mrow1 = mask + (size_t)qrow1 * SEQ;

    for (int t = 0; t < SEQ/64; ++t) {
        const int cur = t & 1;
        if (t + 1 < SEQ/64) STAGE(t + 1, cur ^ 1);

        // mask prefetch (k = 16mf + 4lg + j)
        float4 mk[2][4];
        #pragma unroll
        for (int mf = 0; mf < 4; ++mf) {
            mk[0][mf] = *(const float4*)&mrow0[t*64 + mf*16 + lg*4];
            mk[1][mf] = *(const float4*)&mrow1[t*64 + mf*16 + lg*4];
        }

        // --- S^T = K . Q^T (2-term fp16), both q-frags share every K read ---
        f32x4 st[2][4] = {};
        __builtin_amdgcn_s_setprio(1);
        #pragma unroll
        for (int ks = 0; ks < 2; ++ks) {
            #pragma unroll
            for (int mf = 0; mf < 4; ++mf) {
                const int row = mf*16 + lx;
                const int off = row*128 + ((ks*64 + lg*16) ^ ((row & 7) << 4));
                const short8 akh = *(const short8*)((const char*)&kb[cur][0] + off);
                #pragma unroll
                for (int f = 0; f < 2; ++f) {
                    st[f][mf] = MFMA16(akh, qf[f][0][ks], st[f][mf]);
                    st[f][mf] = MFMA16(akh, qf[f][1][ks], st[f][mf]);
                }
            }
        }
        __builtin_amdgcn_s_setprio(0);

        // --- online softmax per frag (lane owns q-col lx), defer-max THR=8 ---
        unsigned pw[2][4][2];
        #pragma unroll
        for (int f = 0; f < 2; ++f) {
            float p[4][4];
            float mx = -INFINITY;
            #pragma unroll
            for (int mf = 0; mf < 4; ++mf) {
                p[mf][0] = st[f][mf][0]*0.125f + mk[f][mf].x;
                p[mf][1] = st[f][mf][1]*0.125f + mk[f][mf].y;
                p[mf][2] = st[f][mf][2]*0.125f + mk[f][mf].z;
                p[mf][3] = st[f][mf][3]*0.125f + mk[f][mf].w;
                mx = fmaxf(mx, fmaxf(fmaxf(p[mf][0], p[mf][1]), fmaxf(p[mf][2], p[mf][3])));
            }
            mx = fmaxf(mx, __shfl_xor(mx, 16));
            mx = fmaxf(mx, __shfl_xor(mx, 32));

            if (!__all(mx <= m_st[f] + 8.0f)) {      // rescale only on real growth
                const float mnew = fmaxf(m_st[f], mx);
                const float scl = __expf(m_st[f] - mnew);
                m_st[f] = mnew;
                l_st[f] *= scl;
                float fj[4];
                #pragma unroll
                for (int j = 0; j < 4; ++j) fj[j] = __shfl(scl, lg*4 + j);
                #pragma unroll
                for (int nf = 0; nf < 4; ++nf)
                    #pragma unroll
                    for (int j = 0; j < 4; ++j) acc[f][nf][j] *= fj[j];
            }

            float ps = 0.f;
            #pragma unroll
            for (int mf = 0; mf < 4; ++mf) {
                const float e0 = __expf(p[mf][0] - m_st[f]), e1 = __expf(p[mf][1] - m_st[f]);
                const float e2 = __expf(p[mf][2] - m_st[f]), e3 = __expf(p[mf][3] - m_st[f]);
                ps += (e0 + e1) + (e2 + e3);
                pw[f][mf][0] = (unsigned)f2h(e0) | ((unsigned)f2h(e1) << 16);
                pw[f][mf][1] = (unsigned)f2h(e2) | ((unsigned)f2h(e3) << 16);
            }
            ps += __shfl_xor(ps, 16);
            ps += __shfl_xor(ps, 32);
            l_st[f] += ps;
        }

        // --- O += P . V (fp16 single-term), ks-split wave-private P LDS ---
        #pragma unroll
        for (int ks = 0; ks < 2; ++ks) {
            #pragma unroll
            for (int f = 0; f < 2; ++f)
                #pragma unroll
                for (int mm = 0; mm < 2; ++mm) {
                    const int off = lx*64 + ((mm*32 + lg*8) ^ ((lx & 3) << 4));
                    *(uint2*)((char*)&pb[w][f][0] + off) =
                        make_uint2(pw[f][ks*2 + mm][0], pw[f][ks*2 + mm][1]);
                }
            short8 pa[2];
            #pragma unroll
            for (int f = 0; f < 2; ++f) {
                const int poff = lx*64 + ((lg*16) ^ ((lx & 3) << 4));
                pa[f] = *(const short8*)((const char*)&pb[w][f][0] + poff);
            }
            __builtin_amdgcn_s_setprio(1);
            #pragma unroll
            for (int nf = 0; nf < 4; ++nf) {
                const int row = nf*16 + lx;
                const int off = row*128 + ((ks*64 + lg*16) ^ ((row & 7) << 4));
                const short8 vh = *(const short8*)((const char*)&vb[cur][0] + off);
                #pragma unroll
                for (int f = 0; f < 2; ++f)
                    acc[f][nf] = MFMA16(pa[f], vh, acc[f][nf]);
            }
            __builtin_amdgcn_s_setprio(0);
        }

        __syncthreads();
    }

    // epilogue: divide by l, fp16 hi/lo store
    #pragma unroll
    for (int f = 0; f < 2; ++f) {
        float linv[4];
        #pragma unroll
        for (int j = 0; j < 4; ++j) linv[j] = 1.0f / __shfl(l_st[f], lg*4 + j);
        #pragma unroll
        for (int nf = 0; nf < 4; ++nf) {
            const int c = h*HD + nf*16 + lx;
            #pragma unroll
            for (int j = 0; j < 4; ++j) {
                const size_t tok = (size_t)b*SEQ + qblk + w*32 + f*16 + lg*4 + j;
                const float o = acc[f][nf][j] * linv[j];
                const unsigned short hi = f2h(o);
                AOh[tok*DIM + c] = hi;
                AOl[tok*DIM + c] = f2h(o - h2f(hi));
            }
        }
    }
}

// ---------------------------------------------------------------------------
extern "C" void kernel_launch(void* const* d_in, const int* in_sizes, int n_in,
                              void* d_out, int out_size, void* d_ws, size_t ws_size,
                              hipStream_t stream)
{
    const float* x    = (const float*)d_in[0];
    const float* mask = (const float*)d_in[1];
    const float* fc   = (const float*)d_in[2];
    const float* fs   = (const float*)d_in[3];
    const float* wq   = (const float*)d_in[4];
    const float* bq   = (const float*)d_in[5];
    const float* wk   = (const float*)d_in[6];
    const float* bk   = (const float*)d_in[7];
    const float* wv   = (const float*)d_in[8];
    const float* bv   = (const float*)d_in[9];
    const float* wo   = (const float*)d_in[10];
    float* out = (float*)d_out;

    const size_t MB = 1024*1024;
    char* ws = (char*)d_ws;
    unsigned short* Xh  = (unsigned short*)(ws + 0*MB);
    unsigned short* Xl  = (unsigned short*)(ws + 8*MB);
    unsigned short* WT  = (unsigned short*)(ws + 16*MB);   // 4 planes x 2MB (q,k,v,o)
    unsigned short* Qh  = (unsigned short*)(ws + 24*MB);
    unsigned short* Ql  = (unsigned short*)(ws + 32*MB);
    unsigned short* Kh  = (unsigned short*)(ws + 40*MB);
    unsigned short* Vth = (unsigned short*)(ws + 48*MB);
    unsigned short* AOh = Xh;   // reuse after QKV GEMM consumed X planes
    unsigned short* AOl = Xl;

    const size_t WP = (size_t)DIM * DIM;  // weight plane elements

    splitx_kernel<<<(ROWS*DIM)/4/256, 256, 0, stream>>>(x, Xh, Xl);
    splitw_kernel<<<dim3(16, 16, 4), 256, 0, stream>>>(wq, wk, wv, wo, WT);

    gemm3_kernel<0><<<dim3(8, 32, 3), 256, 0, stream>>>(
        Xh, Xl,
        WT, WT + WP, WT + 2*WP,
        bq, bk, bv, fc, fs,
        Qh, Ql, Kh, Vth, nullptr);

    attn_kernel<<<dim3(SEQ/64, NH, BATCH), 128, 0, stream>>>(
        Qh, Ql, Kh, Vth, mask, AOh, AOl);

    gemm3_kernel<1><<<dim3(8, 32, 1), 256, 0, stream>>>(
        AOh, AOl,
        WT + 3*WP, nullptr, nullptr,
        nullptr, nullptr, nullptr, fc, fs,
        nullptr, nullptr, nullptr, nullptr, out);
    (void)in_sizes; (void)n_in; (void)out_size; (void)ws_size;
}